// Round 4
// baseline (226.720 us; speedup 1.0000x reference)
//
#include <hip/hip_runtime.h>
#include <hip/hip_bf16.h>
#include <stdint.h>

#define B_DIM 32768
#define IN_DIM 512
#define OUT_DIM 512

typedef __bf16 bf16;
typedef bf16 bf16x8 __attribute__((ext_vector_type(8)));
typedef float f32x4 __attribute__((ext_vector_type(4)));

// xi = trunc(v*2^sf); keep top-4 significant bits of |xi|; sign restored.
// fp32-bit equivalent: truncf, then mask mantissa to 3 stored bits (+implicit = 4
// significant). Masked fp32 has zero low 16 bits -> top half IS the exact bf16.
__device__ __forceinline__ uint32_t quant2(float a, float b, float scale) {
    uint32_t ua = __float_as_uint(truncf(a * scale)) & 0xFFF00000u;
    uint32_t ub = __float_as_uint(truncf(b * scale)) & 0xFFF00000u;
    return (ua >> 16) | (ub & 0xFFFF0000u);   // packed bf16 pair (a low, b high)
}

__global__ void quant_kernel(const float* __restrict__ in, bf16* __restrict__ out,
                             int n4, const int* __restrict__ sf) {
    int i = blockIdx.x * blockDim.x + threadIdx.x;
    if (i >= n4) return;
    float scale = (float)(1 << *sf);
    float4 v = ((const float4*)in)[i];
    uint2 p;
    p.x = quant2(v.x, v.y, scale);
    p.y = quant2(v.z, v.w, scale);
    ((uint2*)out)[i] = p;
}

// Register-direct fused GEMM: NO LDS, NO barriers.
// C[m,n] = (sum_k q(x[m,k]) * qw[n,k]) * 2^-(asf+wsf) + bias[n]
// MFMA 16x16x32 A/B fragments are 8 contiguous-K elems at row/col=lane&15,
// k=(lane>>4)*8 -- row-major X and W rows load straight into fragments.
// Block = 4 waves stacked in M: tile 256(M) x 64(N). Each wave: 64x64 via 4x4 MFMAs.
// Grid 1024 = 128 bm x 8 bn; XCD swizzle co-locates the 8 bn-blocks of one
// X row-band on one XCD so the 8x X re-read hits that XCD's L2.
__global__ __launch_bounds__(256, 3)
void gemm_rf(const float* __restrict__ X, const bf16* __restrict__ QW,
             const float* __restrict__ bias, float* __restrict__ C,
             const int* __restrict__ wsf, const int* __restrict__ asf) {
    const int t    = threadIdx.x;
    const int w    = t >> 6;
    const int lane = t & 63;

    const int b    = blockIdx.x;
    const int xcd  = b & 7;
    const int slot = b >> 3;              // 0..127
    const int bm   = xcd * 16 + (slot >> 3);
    const int bn   = slot & 7;
    const int row0 = bm * 256 + w * 64;   // this wave's M origin
    const int col0 = bn * 64;

    const int rl = lane & 15;             // fragment row/col within 16
    const int kq = (lane >> 4) * 8;       // fragment k offset within a 32-step

    const float ascale = (float)(1 << *asf);

    // per-fragment base pointers (row-major, contiguous in K)
    const float* Xr[4];
    const bf16*  Wr[4];
    #pragma unroll
    for (int mt = 0; mt < 4; ++mt)
        Xr[mt] = X + (size_t)(row0 + mt * 16 + rl) * IN_DIM + kq;
    #pragma unroll
    for (int nt = 0; nt < 4; ++nt)
        Wr[nt] = QW + (size_t)(col0 + nt * 16 + rl) * IN_DIM + kq;

    f32x4 acc[4][4];
    #pragma unroll
    for (int mt = 0; mt < 4; ++mt)
        #pragma unroll
        for (int nt = 0; nt < 4; ++nt)
            acc[mt][nt] = 0.0f;

    #pragma unroll 2
    for (int k = 0; k < IN_DIM; k += 32) {
        bf16x8 af[4], bfr[4];
        #pragma unroll
        for (int nt = 0; nt < 4; ++nt)
            bfr[nt] = *(const bf16x8*)(Wr[nt] + k);     // 16B bf16 fragment
        #pragma unroll
        for (int mt = 0; mt < 4; ++mt) {
            float4 u = *(const float4*)(Xr[mt] + k);    // 8 fp32 -> quant -> bf16x8
            float4 v = *(const float4*)(Xr[mt] + k + 4);
            uint4 p;
            p.x = quant2(u.x, u.y, ascale);
            p.y = quant2(u.z, u.w, ascale);
            p.z = quant2(v.x, v.y, ascale);
            p.w = quant2(v.z, v.w, ascale);
            af[mt] = *(bf16x8*)&p;
        }
        #pragma unroll
        for (int mt = 0; mt < 4; ++mt)
            #pragma unroll
            for (int nt = 0; nt < 4; ++nt)
                acc[mt][nt] = __builtin_amdgcn_mfma_f32_16x16x32_bf16(af[mt], bfr[nt], acc[mt][nt], 0, 0, 0);
    }

    // epilogue: C/D layout col=lane&15, row=(lane>>4)*4+reg
    const float oscale = ldexpf(1.0f, -(*wsf + *asf));
    const int cl = lane & 15;
    const int rg = (lane >> 4) * 4;
    #pragma unroll
    for (int nt = 0; nt < 4; ++nt) {
        const int col = col0 + nt * 16 + cl;
        const float bv = bias[col];
        #pragma unroll
        for (int mt = 0; mt < 4; ++mt) {
            f32x4 a = acc[mt][nt];
            #pragma unroll
            for (int r = 0; r < 4; ++r) {
                const int row = row0 + mt * 16 + rg + r;
                C[(size_t)row * OUT_DIM + col] = a[r] * oscale + bv;
            }
        }
    }
}

extern "C" void kernel_launch(void* const* d_in, const int* in_sizes, int n_in,
                              void* d_out, int out_size, void* d_ws, size_t ws_size,
                              hipStream_t stream) {
    const float* x    = (const float*)d_in[0];
    const float* wgt  = (const float*)d_in[1];
    const float* bias = (const float*)d_in[2];
    const int*   wsf  = (const int*)d_in[3];
    const int*   asf  = (const int*)d_in[4];

    bf16* tw = (bf16*)d_ws;   // 512 KB quantized weight

    const int nw4 = OUT_DIM * IN_DIM / 4;
    quant_kernel<<<(nw4 + 255) / 256, 256, 0, stream>>>(wgt, tw, nw4, wsf);

    const int grid = (B_DIM / 256) * (OUT_DIM / 64); // 128 x 8 = 1024
    gemm_rf<<<grid, 256, 0, stream>>>(x, tw, bias, (float*)d_out, wsf, asf);
}

// Round 5
// 162.365 us; speedup vs baseline: 1.3964x; 1.3964x over previous
//
#include <hip/hip_runtime.h>
#include <hip/hip_bf16.h>
#include <stdint.h>

#define B_DIM 32768
#define IN_DIM 512
#define OUT_DIM 512
#define BK 32

typedef __bf16 bf16;
typedef bf16 bf16x8 __attribute__((ext_vector_type(8)));
typedef float f32x4 __attribute__((ext_vector_type(4)));

// xi = trunc(v*2^sf); keep top-4 significant bits of |xi|; sign restored.
// fp32-bit equivalent: truncf, then mask mantissa to 3 stored bits (+implicit = 4
// significant). Masked fp32 has zero low 16 bits -> top half IS the exact bf16.
// Packed form: v_perm selects high halves, one AND masks both.
__device__ __forceinline__ uint32_t quant2(float a, float b, float scale) {
    uint32_t ua = __float_as_uint(truncf(a * scale));
    uint32_t ub = __float_as_uint(truncf(b * scale));
    // dst = [ub(hi16) | ua(hi16)], then clear low 4 bits of each half's mantissa
    uint32_t p = __builtin_amdgcn_perm(ub, ua, 0x07060302u);
    return p & 0xFFF0FFF0u;
}

__global__ void quant_kernel(const float* __restrict__ in, bf16* __restrict__ out,
                             int n4, const int* __restrict__ sf) {
    int i = blockIdx.x * blockDim.x + threadIdx.x;
    if (i >= n4) return;
    float scale = (float)(1 << *sf);
    float4 v = ((const float4*)in)[i];
    uint2 p;
    p.x = quant2(v.x, v.y, scale);
    p.y = quant2(v.z, v.w, scale);
    ((uint2*)out)[i] = p;
}

// Fused GEMM: C[m,n] = (sum_k q(x[m,k])*qw[n,k]) * 2^-(asf+wsf) + bias[n]
// A staged as RAW fp32 via async global_load_lds (no register round trip);
// quant applied at fragment-read time. LDS layouts use odd 16B-unit row
// strides (A:9, B:5) chosen through the *source* permutation so fragment
// reads are bank-conflict-free while staging stays 128B-coalesced.
__global__ __launch_bounds__(256, 4)
void gemm_fused(const float* __restrict__ X, const bf16* __restrict__ QW,
                const float* __restrict__ bias, float* __restrict__ C,
                const int* __restrict__ wsf, const int* __restrict__ asf) {
    // A: 128 rows x 9 units (8 real + 1 dup-pad) = 1152 used, 1280 alloc = 20480B
    // B: 128 rows x 5 units (4 real + 1 dup-pad) =  640 used,  768 alloc = 12288B
    __shared__ char smem[32768];
    float* As = (float*)smem;              // indexed in fp32 elems
    bf16*  Bs = (bf16*)(smem + 20480);     // indexed in bf16 elems

    const int t    = threadIdx.x;
    const int w    = t >> 6;
    const int lane = t & 63;

    // XCD swizzle: the 4 N-blocks of one M-band adjacent on one XCD (A L2 reuse)
    const int b    = blockIdx.x;
    const int xcd  = b & 7;
    const int slot = b >> 3;
    const int bm   = xcd * 32 + (slot >> 2);
    const int bn   = slot & 3;
    const int row0 = bm * 128;
    const int col0 = bn * 128;
    const int wm   = (w & 1) * 64;
    const int wn   = (w >> 1) * 64;

    // ---- staging slot -> (source elem offset, LDS byte offset), iter-invariant
    int srcA[5], dstA[5];
    #pragma unroll
    for (int i = 0; i < 5; ++i) {
        int p  = i * 256 + t;              // 16B unit index, 0..1279
        int m  = p / 9;  if (m > 127) m = 127;
        int r  = p - m * 9;
        int ku = (r >= 8) ? 0 : r;         // pad unit re-stages ku=0 (harmless dup)
        srcA[i] = (row0 + m) * IN_DIM + ku * 4;   // fp32 elems
        dstA[i] = p * 16;                          // bytes
    }
    int srcB[3], dstB[3];
    #pragma unroll
    for (int i = 0; i < 3; ++i) {
        int p  = i * 256 + t;              // 0..767
        int m  = p / 5;  if (m > 127) m = 127;
        int r  = p - m * 5;
        int ku = (r >= 4) ? 0 : r;
        srcB[i] = (col0 + m) * IN_DIM + ku * 8;   // bf16 elems
        dstB[i] = p * 16;
    }

    const float ascale = (float)(1 << *asf);
    const int q  = lane >> 4;              // k-quad 0..3
    const int rl = lane & 15;

    f32x4 acc[4][4];
    #pragma unroll
    for (int mt = 0; mt < 4; ++mt)
        #pragma unroll
        for (int nt = 0; nt < 4; ++nt)
            acc[mt][nt] = 0.0f;

    for (int k0 = 0; k0 < IN_DIM; k0 += BK) {
        // async staging: A fp32 (5 issues) + B bf16 (3 issues), 16B/lane
        #pragma unroll
        for (int i = 0; i < 5; ++i)
            __builtin_amdgcn_global_load_lds(
                (const __attribute__((address_space(1))) void*)(X + srcA[i] + k0),
                (__attribute__((address_space(3))) void*)(smem + dstA[i]), 16, 0, 0);
        #pragma unroll
        for (int i = 0; i < 3; ++i)
            __builtin_amdgcn_global_load_lds(
                (const __attribute__((address_space(1))) void*)(QW + srcB[i] + k0),
                (__attribute__((address_space(3))) void*)(smem + 20480 + dstB[i]), 16, 0, 0);
        __syncthreads();

        bf16x8 af[4], bfr[4];
        #pragma unroll
        for (int mt = 0; mt < 4; ++mt) {
            const int m = wm + mt * 16 + rl;
            const float* p = As + (9 * m + 2 * q) * 4;   // unit (9m+2q), 8 fp32
            f32x4 u = *(const f32x4*)p;
            f32x4 v = *(const f32x4*)(p + 4);
            uint4 pk;
            pk.x = quant2(u[0], u[1], ascale);
            pk.y = quant2(u[2], u[3], ascale);
            pk.z = quant2(v[0], v[1], ascale);
            pk.w = quant2(v[2], v[3], ascale);
            af[mt] = *(bf16x8*)&pk;
        }
        #pragma unroll
        for (int nt = 0; nt < 4; ++nt) {
            const int c = wn + nt * 16 + rl;
            bfr[nt] = *(const bf16x8*)(Bs + (5 * c + q) * 8);
        }
        #pragma unroll
        for (int mt = 0; mt < 4; ++mt)
            #pragma unroll
            for (int nt = 0; nt < 4; ++nt)
                acc[mt][nt] = __builtin_amdgcn_mfma_f32_16x16x32_bf16(af[mt], bfr[nt], acc[mt][nt], 0, 0, 0);
        __syncthreads();
    }

    // epilogue: C/D layout col=lane&15, row=(lane>>4)*4+reg
    const float oscale = ldexpf(1.0f, -(*wsf + *asf));
    const int cl = lane & 15;
    const int rg = (lane >> 4) * 4;
    #pragma unroll
    for (int nt = 0; nt < 4; ++nt) {
        const int col = col0 + wn + nt * 16 + cl;
        const float bv = bias[col];
        #pragma unroll
        for (int mt = 0; mt < 4; ++mt) {
            f32x4 a = acc[mt][nt];
            #pragma unroll
            for (int r = 0; r < 4; ++r) {
                const int row = row0 + wm + mt * 16 + rg + r;
                C[(size_t)row * OUT_DIM + col] = a[r] * oscale + bv;
            }
        }
    }
}

extern "C" void kernel_launch(void* const* d_in, const int* in_sizes, int n_in,
                              void* d_out, int out_size, void* d_ws, size_t ws_size,
                              hipStream_t stream) {
    const float* x    = (const float*)d_in[0];
    const float* wgt  = (const float*)d_in[1];
    const float* bias = (const float*)d_in[2];
    const int*   wsf  = (const int*)d_in[3];
    const int*   asf  = (const int*)d_in[4];

    bf16* tw = (bf16*)d_ws;   // 512 KB quantized weight

    const int nw4 = OUT_DIM * IN_DIM / 4;
    quant_kernel<<<(nw4 + 255) / 256, 256, 0, stream>>>(wgt, tw, nw4, wsf);

    const int grid = (B_DIM / 128) * (OUT_DIM / 128); // 1024
    gemm_fused<<<grid, 256, 0, stream>>>(x, tw, bias, (float*)d_out, wsf, asf);
}

// Round 6
// 137.917 us; speedup vs baseline: 1.6439x; 1.1773x over previous
//
#include <hip/hip_runtime.h>
#include <hip/hip_bf16.h>
#include <stdint.h>

#define B_DIM 32768
#define IN_DIM 512
#define OUT_DIM 512

typedef __bf16 bf16;
typedef bf16 bf16x8 __attribute__((ext_vector_type(8)));
typedef float f32x4 __attribute__((ext_vector_type(4)));

// xi = trunc(v*2^sf); keep top-4 significant bits of |xi|; sign restored.
// fp32-bit equivalent: truncf, then mask mantissa to 3 stored bits (+implicit=4
// significant). Masked fp32 has zero low 16 bits -> top half IS the exact bf16.
// Packed: v_perm gathers both high halves, one AND masks both (verified absmax=0).
__device__ __forceinline__ uint32_t quant2(float a, float b, float scale) {
    uint32_t ua = __float_as_uint(truncf(a * scale));
    uint32_t ub = __float_as_uint(truncf(b * scale));
    uint32_t p = __builtin_amdgcn_perm(ub, ua, 0x07060302u);
    return p & 0xFFF0FFF0u;
}

__global__ void quant_kernel(const float* __restrict__ in, bf16* __restrict__ out,
                             int n4, const int* __restrict__ sf) {
    int i = blockIdx.x * blockDim.x + threadIdx.x;
    if (i >= n4) return;
    float scale = (float)(1 << *sf);
    float4 v = ((const float4*)in)[i];
    uint2 p;
    p.x = quant2(v.x, v.y, scale);
    p.y = quant2(v.z, v.w, scale);
    ((uint2*)out)[i] = p;
}

// bf16 GEMM (R1 structure + XOR-swizzled LDS + XCD swizzle):
// C[m,n] = (sum_k qx[m,k]*qw[n,k]) * 2^-(asf+wsf) + bias[n]
// 128x128 tile, BK=64, 4 waves 2x2, 4x4 of 16x16x32 MFMA per wave.
// LDS layout: row m's 16B k-unit ku lives at physical unit m*8 + (ku^(m&7)).
// The permutation is applied on the GLOBAL side of global_load_lds (per-lane
// source addresses are free; dst is locked to base+lane*16). Fragment b128
// reads then hit all 8 bank groups x 8 lanes -> conflict-free.
__global__ __launch_bounds__(256, 4)
void gemm_bt(const bf16* __restrict__ A, const bf16* __restrict__ W,
             const float* __restrict__ bias, float* __restrict__ C,
             const int* __restrict__ wsf, const int* __restrict__ asf) {
    __shared__ bf16 As[128 * 64];
    __shared__ bf16 Bs[128 * 64];

    const int t    = threadIdx.x;
    const int w    = t >> 6;
    const int lane = t & 63;

    // XCD swizzle: 4 N-blocks of one M-band adjacent on one XCD (A L2 reuse).
    const int b    = blockIdx.x;
    const int xcd  = b & 7;
    const int slot = b >> 3;
    const int bm   = xcd * 32 + (slot >> 2);
    const int bn   = slot & 3;
    const int row0 = bm * 128;
    const int col0 = bn * 128;
    const int wm   = (w & 1) * 64;
    const int wn   = (w >> 1) * 64;

    // staging: thread t covers physical unit p = i*256 + t; row m = p>>3,
    // slot j = p&7 holds logical k-unit ku = j ^ (m&7).
    const int m_st = t >> 3;                    // 0..31 (+i*32; i*32 === 0 mod 8)
    const int ku   = (t & 7) ^ (m_st & 7);
    const size_t offA = (size_t)(row0 + m_st) * IN_DIM + ku * 8;
    const size_t offB = (size_t)(col0 + m_st) * IN_DIM + ku * 8;

    f32x4 acc[4][4];
    #pragma unroll
    for (int mt = 0; mt < 4; ++mt)
        #pragma unroll
        for (int nt = 0; nt < 4; ++nt)
            acc[mt][nt] = 0.0f;

    for (int k0 = 0; k0 < IN_DIM; k0 += 64) {
        #pragma unroll
        for (int i = 0; i < 4; ++i) {
            const bf16* ga = A + offA + (size_t)i * 32 * IN_DIM + k0;
            bf16*       la = As + (i * 256 + w * 64) * 8;   // + lane*8 elems by HW
            __builtin_amdgcn_global_load_lds((const __attribute__((address_space(1))) void*)ga,
                                             (__attribute__((address_space(3))) void*)la, 16, 0, 0);
            const bf16* gb = W + offB + (size_t)i * 32 * IN_DIM + k0;
            bf16*       lb = Bs + (i * 256 + w * 64) * 8;
            __builtin_amdgcn_global_load_lds((const __attribute__((address_space(1))) void*)gb,
                                             (__attribute__((address_space(3))) void*)lb, 16, 0, 0);
        }
        __syncthreads();

        const int q  = lane >> 4;
        const int rl = lane & 15;
        const int sx = rl & 7;                  // = m&7 (wm, mt*16 are mult of 8)
        #pragma unroll
        for (int ks = 0; ks < 2; ++ks) {
            const int c = ks * 4 + q;           // logical k-unit
            const int cs = (c ^ sx) * 8;        // swizzled, in elems
            bf16x8 af[4], bfr[4];
            #pragma unroll
            for (int mt = 0; mt < 4; ++mt)
                af[mt] = *(const bf16x8*)(As + (wm + mt * 16 + rl) * 64 + cs);
            #pragma unroll
            for (int nt = 0; nt < 4; ++nt)
                bfr[nt] = *(const bf16x8*)(Bs + (wn + nt * 16 + rl) * 64 + cs);
            #pragma unroll
            for (int mt = 0; mt < 4; ++mt)
                #pragma unroll
                for (int nt = 0; nt < 4; ++nt)
                    acc[mt][nt] = __builtin_amdgcn_mfma_f32_16x16x32_bf16(af[mt], bfr[nt], acc[mt][nt], 0, 0, 0);
        }
        __syncthreads();
    }

    // epilogue: C/D layout col=lane&15, row=(lane>>4)*4+reg
    const float oscale = ldexpf(1.0f, -(*wsf + *asf));
    const int cl = lane & 15;
    const int rg = (lane >> 4) * 4;
    #pragma unroll
    for (int nt = 0; nt < 4; ++nt) {
        const int col = col0 + wn + nt * 16 + cl;
        const float bv = bias[col];
        #pragma unroll
        for (int mt = 0; mt < 4; ++mt) {
            f32x4 a = acc[mt][nt];
            #pragma unroll
            for (int r = 0; r < 4; ++r) {
                const int row = row0 + wm + mt * 16 + rg + r;
                C[(size_t)row * OUT_DIM + col] = a[r] * oscale + bv;
            }
        }
    }
}

extern "C" void kernel_launch(void* const* d_in, const int* in_sizes, int n_in,
                              void* d_out, int out_size, void* d_ws, size_t ws_size,
                              hipStream_t stream) {
    const float* x    = (const float*)d_in[0];
    const float* wgt  = (const float*)d_in[1];
    const float* bias = (const float*)d_in[2];
    const int*   wsf  = (const int*)d_in[3];
    const int*   asf  = (const int*)d_in[4];

    bf16* tx = (bf16*)d_ws;
    bf16* tw = (bf16*)((char*)d_ws + (size_t)B_DIM * IN_DIM * sizeof(bf16));

    const int nx4 = B_DIM * IN_DIM / 4;
    const int nw4 = OUT_DIM * IN_DIM / 4;
    quant_kernel<<<(nx4 + 255) / 256, 256, 0, stream>>>(x, tx, nx4, asf);
    quant_kernel<<<(nw4 + 255) / 256, 256, 0, stream>>>(wgt, tw, nw4, wsf);

    const int grid = (B_DIM / 128) * (OUT_DIM / 128); // 1024
    gemm_bt<<<grid, 256, 0, stream>>>(tx, tw, bias, (float*)d_out, wsf, asf);
}